// Round 15
// baseline (765.122 us; speedup 1.0000x reference)
//
#include <hip/hip_runtime.h>
#include <hip/hip_bf16.h>

typedef _Float16 f16;
typedef f16 f16x4 __attribute__((ext_vector_type(4)));
typedef f16 f16x8 __attribute__((ext_vector_type(8)));
typedef float f32x4 __attribute__((ext_vector_type(4)));

#define T_LEN 784
#define BATCH 64
#define DH 512
#define NCH (BATCH*DH)        // 32768 chains
#define M_ROWS (T_LEN*BATCH)  // 50176
#define NCHUNK 16
#define CLEN 49               // 784 = 16*49

#define ACT_SCALE (1.0f/256.0f)   // power-of-2 activation scaling: exact, keeps fp16 in range
#define ACT_INV   256.0f

// global -> LDS direct DMA, 16B per lane; dest = wave-uniform base + lane*16 (m104/m108)
#define GLL16(g, s)                                                             \
    __builtin_amdgcn_global_load_lds(                                           \
        (const __attribute__((address_space(1))) void*)(g),                     \
        (__attribute__((address_space(3))) void*)(s), 16, 0, 0)

#define VMCNT(n) asm volatile("s_waitcnt vmcnt(" #n ")" ::: "memory")

// ---------------- weight prep: fp32 [k][n] -> fp16 [n][k] (transpose+convert) ----------------
__global__ void prep_weights(const float* __restrict__ B, const float* __restrict__ C,
                             f16* __restrict__ Bt, f16* __restrict__ Ct) {
    __shared__ float tile[32][33];
    int z = blockIdx.z;  // 0..2: B layer z ; 3..5: C layer z-3
    const float* src = (z < 3) ? (B + (size_t)z * DH * DH) : (C + (size_t)(z - 3) * DH * DH);
    f16* dst = (z < 3) ? (Bt + (size_t)z * DH * DH) : (Ct + (size_t)(z - 3) * DH * DH);
    int tx = threadIdx.x, ty = threadIdx.y;  // 32 x 8
    int nb = blockIdx.x * 32, kb = blockIdx.y * 32;
#pragma unroll
    for (int i = 0; i < 4; i++) {
        int k = ty + i * 8;
        tile[k][tx] = src[(size_t)(kb + k) * DH + nb + tx];
    }
    __syncthreads();
#pragma unroll
    for (int i = 0; i < 4; i++) {
        int n = ty + i * 8;
        dst[(size_t)(nb + n) * DH + kb + tx] = (f16)tile[tx][n];
    }
}

// ---------------- first dense: H = relu(x @ W0 + b0) * ACT_SCALE, fp16 out ----------------
__global__ void dense0_kernel(const float* __restrict__ x, const float* __restrict__ W0,
                              const float* __restrict__ b0, f16* __restrict__ H) {
    int tid = blockIdx.x * 256 + threadIdx.x;
    int m = tid >> 6;
    int hb = (tid & 63) * 8;
    float x0 = x[(size_t)m * 2], x1 = x[(size_t)m * 2 + 1];
    f32x4 wa0 = *(const f32x4*)(W0 + hb);
    f32x4 wa1 = *(const f32x4*)(W0 + hb + 4);
    f32x4 wb0 = *(const f32x4*)(W0 + DH + hb);
    f32x4 wb1 = *(const f32x4*)(W0 + DH + hb + 4);
    f32x4 c0 = *(const f32x4*)(b0 + hb);
    f32x4 c1 = *(const f32x4*)(b0 + hb + 4);
    f16x8 o;
#pragma unroll
    for (int j = 0; j < 4; j++) {
        float v = fmaxf(fmaf(x0, wa0[j], fmaf(x1, wb0[j], c0[j])), 0.f) * ACT_SCALE;
        o[j] = (f16)v;
    }
#pragma unroll
    for (int j = 0; j < 4; j++) {
        float v = fmaxf(fmaf(x0, wa1[j], fmaf(x1, wb1[j], c1[j])), 0.f) * ACT_SCALE;
        o[4 + j] = (f16)v;
    }
    *(f16x8*)(H + (size_t)m * DH + hb) = o;
}

// ---------------- persistent multi-tile fp16 MFMA GEMM: Out[M,512] = A[M,512] @ Bt^T -------
// R12's verified K-loop rhythm (128x128 tile, BK=32, 4 waves, 3-slot ring, VMCNT(4)+barrier,
// stage s+2) run as ONE CONTINUOUS 112-step stream per block over 7 row-tiles at a FIXED
// column: grid 224 = 56 row-groups x 4 cols; nb constant per block (B pointers fixed),
// mb = (r0 + s/16)*128 (shift-only). The pipeline never drains across tile boundaries --
// amortizes the ~6k-cyc per-block ramp that R5-R14 paid every 16 K-steps (the invariant
// behind the 44us plateau). Per-tile epilogue = R6-verified swapped-operand mfma(bg,af)
// layout -> 16x 8B f16x4 stores, issued in-stream (vmcnt pollution only over-syncs the
// next step; safe). Tail steps use VMCNT(0). XOR-swizzled k-slots (rule #21).
template <int RELU>
__global__ __launch_bounds__(256) void gemm_p(const f16* __restrict__ A,
                                              const f16* __restrict__ Bt,
                                              f16* __restrict__ Out) {
    __shared__ __align__(16) f16 As[3][128 * 32];
    __shared__ __align__(16) f16 Bs[3][128 * 32];
    const int tid = threadIdx.x;
    const int lane = tid & 63;
    const int wave = tid >> 6;
    const int wr = wave >> 1, wc = wave & 1;
    const int blk = blockIdx.x;          // 0..223
    const int nb = (blk / 56) * 128;     // fixed column per block
    const int r0 = (blk % 56) * 7;       // first row-tile

    // staging: wave w, round p covers rows [p*64 + w*16, +16); lane l -> row +(l>>2), slot l&3
    const int rl = lane >> 2, sl = lane & 3;
    const int ssl = sl ^ ((rl >> 1) & 3);             // pre-swizzled source k-slot
    const int rowS0 = wave * 16 + rl;                 // round 0 row (within tile)
    const int rowS1 = 64 + wave * 16 + rl;            // round 1 row
    const f16* gB0 = Bt + (size_t)(nb + rowS0) * DH + ssl * 8;   // B fixed all 7 tiles
    const f16* gB1 = Bt + (size_t)(nb + rowS1) * DH + ssl * 8;
    const int ldsOff0 = (wave * 16) * 32;             // wave-uniform LDS elem offsets
    const int ldsOff1 = (64 + wave * 16) * 32;

    // fragment read offsets: row = w*64 + i*16 + rA, k-slot kq swizzled by f(rA)
    const int rA = lane & 15, kq = lane >> 4;
    const int fsl = kq ^ ((rA >> 1) & 3);
    int offA[4], offB[4];
#pragma unroll
    for (int i = 0; i < 4; i++) offA[i] = (wr * 64 + i * 16 + rA) * 32 + fsl * 8;
#pragma unroll
    for (int j = 0; j < 4; j++) offB[j] = (wc * 64 + j * 16 + rA) * 32 + fsl * 8;

    f32x4 acc[4][4] = {};

    // stage global step s2 into ring slot `slot`: tile = s2>>4, k-offset = (s2&15)*32
#define STAGE_S(s2, slot)                                                          \
    do {                                                                           \
        int ti_ = (s2) >> 4;                                                       \
        int kt_ = ((s2) & 15) * 32;                                                \
        const f16* a0 = A + ((size_t)((r0 + ti_) * 128 + rowS0)) * DH + kt_ + ssl * 8; \
        const f16* a1 = A + ((size_t)((r0 + ti_) * 128 + rowS1)) * DH + kt_ + ssl * 8; \
        GLL16(a0, &As[slot][ldsOff0]);                                             \
        GLL16(a1, &As[slot][ldsOff1]);                                             \
        GLL16(gB0 + kt_, &Bs[slot][ldsOff0]);                                      \
        GLL16(gB1 + kt_, &Bs[slot][ldsOff1]);                                      \
    } while (0)

    // swapped operands (R6-verified): lane owns row = i*16+(lane&15),
    // cols = j*16 + (lane>>4)*4 + 0..3
#define COMPUTE(b)                                                                              \
    do {                                                                                        \
        f16x8 af[4], bg[4];                                                                     \
        _Pragma("unroll") for (int i = 0; i < 4; i++) af[i] = *(const f16x8*)&As[b][offA[i]];   \
        _Pragma("unroll") for (int j = 0; j < 4; j++) bg[j] = *(const f16x8*)&Bs[b][offB[j]];   \
        _Pragma("unroll") for (int i = 0; i < 4; i++)                                           \
        _Pragma("unroll") for (int j = 0; j < 4; j++)                                           \
            acc[i][j] = __builtin_amdgcn_mfma_f32_16x16x32_f16(bg[j], af[i], acc[i][j], 0, 0, 0); \
    } while (0)

    // prologue: depth-2
    STAGE_S(0, 0);
    STAGE_S(1, 1);

    const int erow = lane & 15;
    const int ecq = (lane >> 4) * 4;
    int cb = 0, sb = 2;  // compute slot = s%3, stage slot = (s+2)%3
    for (int s = 0; s < 112; ++s) {
        if (s < 110) { VMCNT(4); } else { VMCNT(0); }  // s>=110: no deeper stage in flight
        __builtin_amdgcn_s_barrier();                   // all waves' stage-s landed; s-1 reads done
        if (s < 110) STAGE_S(s + 2, sb);
        COMPUTE(cb);
        if ((s & 15) == 15) {
            // epilogue for tile s>>4 (stores overlap subsequent staging; vmcnt over-sync only)
            size_t mb = (size_t)(r0 + (s >> 4)) * 128;
#pragma unroll
            for (int i = 0; i < 4; i++) {
                size_t row = mb + wr * 64 + i * 16 + erow;
#pragma unroll
                for (int j = 0; j < 4; j++) {
                    int col = nb + wc * 64 + j * 16 + ecq;
                    f16x4 o;
#pragma unroll
                    for (int r = 0; r < 4; r++) {
                        float v = acc[i][j][r];
                        if (RELU) v = fmaxf(v, 0.f);
                        o[r] = (f16)v;
                    }
                    *(f16x4*)(Out + row * DH + col) = o;
                }
            }
#pragma unroll
            for (int i = 0; i < 4; i++)
#pragma unroll
                for (int j = 0; j < 4; j++) acc[i][j] = (f32x4){0.f, 0.f, 0.f, 0.f};
        }
        cb = (cb == 2) ? 0 : cb + 1;
        sb = (sb == 2) ? 0 : sb + 1;
    }
#undef STAGE_S
#undef COMPUTE
}

// ---------------- chunked diagonal scan over T (h_t = a*h_{t-1} + u_t) ----------------
__global__ void scan_pass1(const f16* __restrict__ U, const float* __restrict__ Al,
                           float* __restrict__ finals) {
    int tid = blockIdx.x * 256 + threadIdx.x;  // 524288 threads
    int ch = tid & (NCH - 1);
    int c = tid >> 15;
    float a = Al[ch & (DH - 1)];
    const f16* p = U + (size_t)(c * CLEN) * NCH + ch;
    float h = 0.f;
#pragma unroll
    for (int i = 0; i < CLEN; i++) h = fmaf(h, a, (float)p[(size_t)i * NCH]);
    finals[(size_t)c * NCH + ch] = h;
}

// pass3 with pass2 merged (R12, verified): recompute chunk carry from `finals` in-thread.
__global__ void scan_pass3(f16* __restrict__ U, const float* __restrict__ Al,
                           const float* __restrict__ finals) {
    int tid = blockIdx.x * 256 + threadIdx.x;
    int ch = tid & (NCH - 1);
    int c = tid >> 15;
    float a = Al[ch & (DH - 1)];
    float a49 = 1.f;
#pragma unroll
    for (int i = 0; i < CLEN; i++) a49 *= a;
    float carry = 0.f;
    for (int cc = 0; cc < c; cc++)
        carry = fmaf(carry, a49, finals[(size_t)cc * NCH + ch]);
    f16* p = U + (size_t)(c * CLEN) * NCH + ch;
    float h = carry;
#pragma unroll
    for (int i = 0; i < CLEN; i++) {
        h = fmaf(h, a, (float)p[(size_t)i * NCH]);
        p[(size_t)i * NCH] = (f16)h;
    }
}

// ---------------- final dense: out[m,0:2] = (H[m,:] @ Wf) * ACT_INV + bf ----------------
__global__ void final_dense(const f16* __restrict__ H, const float* __restrict__ Wf,
                            const float* __restrict__ bf_, float* __restrict__ out) {
    __shared__ float WfS[DH * 2];
    for (int i = threadIdx.x; i < DH * 2; i += 256) WfS[i] = Wf[i];
    __syncthreads();
    int wave = threadIdx.x >> 6, lane = threadIdx.x & 63;
    size_t m = (size_t)blockIdx.x * 4 + wave;
    f16x8 v = *(const f16x8*)(H + m * DH + lane * 8);
    float d0 = 0.f, d1 = 0.f;
#pragma unroll
    for (int j = 0; j < 8; j++) {
        float hv = (float)v[j];
        int h = lane * 8 + j;
        d0 = fmaf(hv, WfS[h * 2], d0);
        d1 = fmaf(hv, WfS[h * 2 + 1], d1);
    }
#pragma unroll
    for (int off = 32; off; off >>= 1) {
        d0 += __shfl_down(d0, off);
        d1 += __shfl_down(d1, off);
    }
    if (lane == 0) {
        out[m * 2] = fmaf(d0, ACT_INV, bf_[0]);
        out[m * 2 + 1] = fmaf(d1, ACT_INV, bf_[1]);
    }
}

extern "C" void kernel_launch(void* const* d_in, const int* in_sizes, int n_in,
                              void* d_out, int out_size, void* d_ws, size_t ws_size,
                              hipStream_t stream) {
    (void)in_sizes; (void)n_in; (void)out_size; (void)ws_size;
    const float* x   = (const float*)d_in[0];
    const float* W0  = (const float*)d_in[1];
    const float* b0  = (const float*)d_in[2];
    const float* A   = (const float*)d_in[3];
    const float* Bw  = (const float*)d_in[4];
    const float* Cw  = (const float*)d_in[5];
    const float* Wf  = (const float*)d_in[6];
    const float* bfv = (const float*)d_in[7];
    float* out = (float*)d_out;

    char* ws = (char*)d_ws;
    size_t off = 0;
    auto alloc = [&](size_t bytes) {
        void* p = ws + off;
        off += (bytes + 255) & ~(size_t)255;
        return p;
    };
    f16* Bt = (f16*)alloc((size_t)3 * DH * DH * 2);
    f16* Ct = (f16*)alloc((size_t)3 * DH * DH * 2);
    f16* P  = (f16*)alloc((size_t)M_ROWS * DH * 2);  // layer activations
    f16* Q  = (f16*)alloc((size_t)M_ROWS * DH * 2);  // u / hs buffer
    float* finals  = (float*)alloc((size_t)NCH * NCHUNK * 4);

    dim3 b256(256);
    prep_weights<<<dim3(16, 16, 6), dim3(32, 8), 0, stream>>>(Bw, Cw, Bt, Ct);
    dense0_kernel<<<M_ROWS * 64 / 256, b256, 0, stream>>>(x, W0, b0, P);
    for (int l = 0; l < 3; l++) {
        const float* Al = A + l * DH;
        gemm_p<0><<<dim3(224), b256, 0, stream>>>(P, Bt + (size_t)l * DH * DH, Q);
        scan_pass1<<<NCH * NCHUNK / 256, b256, 0, stream>>>(Q, Al, finals);
        scan_pass3<<<NCH * NCHUNK / 256, b256, 0, stream>>>(Q, Al, finals);
        gemm_p<1><<<dim3(224), b256, 0, stream>>>(Q, Ct + (size_t)l * DH * DH, P);
    }
    final_dense<<<M_ROWS / 4, b256, 0, stream>>>(P, Wf, bfv, out);
}

// Round 16
// 519.165 us; speedup vs baseline: 1.4738x; 1.4738x over previous
//
#include <hip/hip_runtime.h>
#include <hip/hip_bf16.h>

typedef _Float16 f16;
typedef f16 f16x4 __attribute__((ext_vector_type(4)));
typedef f16 f16x8 __attribute__((ext_vector_type(8)));
typedef float f32x4 __attribute__((ext_vector_type(4)));

#define T_LEN 784
#define BATCH 64
#define DH 512
#define NCH (BATCH*DH)        // 32768 chains
#define M_ROWS (T_LEN*BATCH)  // 50176
#define NCHUNK 16
#define CLEN 49               // 784 = 16*49

#define ACT_SCALE (1.0f/256.0f)   // power-of-2 activation scaling: exact, keeps fp16 in range
#define ACT_INV   256.0f

// global -> LDS direct DMA, 16B per lane; dest = wave-uniform base + lane*16 (m104/m108)
#define GLL16(g, s)                                                             \
    __builtin_amdgcn_global_load_lds(                                           \
        (const __attribute__((address_space(1))) void*)(g),                     \
        (__attribute__((address_space(3))) void*)(s), 16, 0, 0)

#define VMCNT(n) asm volatile("s_waitcnt vmcnt(" #n ")" ::: "memory")

// ---------------- weight prep: fp32 [k][n] -> fp16 [n][k] (transpose+convert) ----------------
__global__ void prep_weights(const float* __restrict__ B, const float* __restrict__ C,
                             f16* __restrict__ Bt, f16* __restrict__ Ct) {
    __shared__ float tile[32][33];
    int z = blockIdx.z;  // 0..2: B layer z ; 3..5: C layer z-3
    const float* src = (z < 3) ? (B + (size_t)z * DH * DH) : (C + (size_t)(z - 3) * DH * DH);
    f16* dst = (z < 3) ? (Bt + (size_t)z * DH * DH) : (Ct + (size_t)(z - 3) * DH * DH);
    int tx = threadIdx.x, ty = threadIdx.y;  // 32 x 8
    int nb = blockIdx.x * 32, kb = blockIdx.y * 32;
#pragma unroll
    for (int i = 0; i < 4; i++) {
        int k = ty + i * 8;
        tile[k][tx] = src[(size_t)(kb + k) * DH + nb + tx];
    }
    __syncthreads();
#pragma unroll
    for (int i = 0; i < 4; i++) {
        int n = ty + i * 8;
        dst[(size_t)(nb + n) * DH + kb + tx] = (f16)tile[tx][n];
    }
}

// ---------------- first dense: H = relu(x @ W0 + b0) * ACT_SCALE, fp16 out ----------------
__global__ void dense0_kernel(const float* __restrict__ x, const float* __restrict__ W0,
                              const float* __restrict__ b0, f16* __restrict__ H) {
    int tid = blockIdx.x * 256 + threadIdx.x;
    int m = tid >> 6;
    int hb = (tid & 63) * 8;
    float x0 = x[(size_t)m * 2], x1 = x[(size_t)m * 2 + 1];
    f32x4 wa0 = *(const f32x4*)(W0 + hb);
    f32x4 wa1 = *(const f32x4*)(W0 + hb + 4);
    f32x4 wb0 = *(const f32x4*)(W0 + DH + hb);
    f32x4 wb1 = *(const f32x4*)(W0 + DH + hb + 4);
    f32x4 c0 = *(const f32x4*)(b0 + hb);
    f32x4 c1 = *(const f32x4*)(b0 + hb + 4);
    f16x8 o;
#pragma unroll
    for (int j = 0; j < 4; j++) {
        float v = fmaxf(fmaf(x0, wa0[j], fmaf(x1, wb0[j], c0[j])), 0.f) * ACT_SCALE;
        o[j] = (f16)v;
    }
#pragma unroll
    for (int j = 0; j < 4; j++) {
        float v = fmaxf(fmaf(x0, wa1[j], fmaf(x1, wb1[j], c1[j])), 0.f) * ACT_SCALE;
        o[4 + j] = (f16)v;
    }
    *(f16x8*)(H + (size_t)m * DH + hb) = o;
}

// ---------------- persistent 2-tile fp16 MFMA GEMM: Out[M,512] = A[M,512] @ Bt^T -----------
// Clean retest of the ramp hypothesis with TLP HELD CONSTANT (R15 confounded it):
// R12's verified rhythm (128x128 tile, BK=32, 4 waves, 3-slot ring, VMCNT+barrier, stage
// s+2), but each block runs 32 CONTINUOUS K-steps over 2 row-tiles at a fixed column.
// Grid 784 = 196 row-groups x 4 cols (col = blk&3 -> A-panel col-mates adjacent);
// 784/256 = 3.06 blocks/CU, LDS 48KB -> 3 co-resident = 12 waves/CU (same as R12).
// Fully unrolled: compile-time ring slots (R15's dynamic loop cost 25% VALU).
// Mid-stream epilogue at s=15 leaves 16 stores in the vmem queue: steps s=16,17 use
// VMCNT(20) (drains exactly the oldest load-group past 16 stores + 4 newer loads),
// all other steps VMCNT(4); tail VMCNT(0). Swapped-operand mfma(bg,af) epilogue
// (R6/R15-verified): lane owns 4 consecutive out-cols of one row -> 8B stores.
// XOR-swizzled k-slots (rule #21).
template <int RELU>
__global__ __launch_bounds__(256) void gemm_p(const f16* __restrict__ A,
                                              const f16* __restrict__ Bt,
                                              f16* __restrict__ Out) {
    __shared__ __align__(16) f16 As[3][128 * 32];
    __shared__ __align__(16) f16 Bs[3][128 * 32];
    const int tid = threadIdx.x;
    const int lane = tid & 63;
    const int wave = tid >> 6;
    const int wr = wave >> 1, wc = wave & 1;
    const int blk = blockIdx.x;          // 0..783
    const int nb = (blk & 3) * 128;      // fixed column per block
    const int r0 = (blk >> 2) * 2;       // first of 2 row-tiles

    // staging: wave w, round p covers rows [p*64 + w*16, +16); lane l -> row +(l>>2), slot l&3
    const int rl = lane >> 2, sl = lane & 3;
    const int ssl = sl ^ ((rl >> 1) & 3);             // pre-swizzled source k-slot
    const int rowS0 = wave * 16 + rl;                 // round 0 row (within tile)
    const int rowS1 = 64 + wave * 16 + rl;            // round 1 row
    const f16* gA0 = A + ((size_t)r0 * 128 + rowS0) * DH + ssl * 8;  // tile 0; tile 1 = +128*DH
    const f16* gA1 = A + ((size_t)r0 * 128 + rowS1) * DH + ssl * 8;
    const f16* gB0 = Bt + (size_t)(nb + rowS0) * DH + ssl * 8;       // B fixed both tiles
    const f16* gB1 = Bt + (size_t)(nb + rowS1) * DH + ssl * 8;
    const int ldsOff0 = (wave * 16) * 32;             // wave-uniform LDS elem offsets
    const int ldsOff1 = (64 + wave * 16) * 32;

    // fragment read offsets: row = w*64 + i*16 + rA, k-slot kq swizzled by f(rA)
    const int rA = lane & 15, kq = lane >> 4;
    const int fsl = kq ^ ((rA >> 1) & 3);
    int offA[4], offB[4];
#pragma unroll
    for (int i = 0; i < 4; i++) offA[i] = (wr * 64 + i * 16 + rA) * 32 + fsl * 8;
#pragma unroll
    for (int j = 0; j < 4; j++) offB[j] = (wc * 64 + j * 16 + rA) * 32 + fsl * 8;

    f32x4 acc[4][4] = {};

    // stage global step s2 (0..31): tile = s2>>4, k-offset = (s2&15)*32
#define STAGE_S(s2, slot)                                          \
    do {                                                           \
        size_t ao_ = (size_t)((s2) >> 4) * 128 * DH + ((s2) & 15) * 32; \
        int kt_ = ((s2) & 15) * 32;                                \
        GLL16(gA0 + ao_, &As[slot][ldsOff0]);                      \
        GLL16(gA1 + ao_, &As[slot][ldsOff1]);                      \
        GLL16(gB0 + kt_, &Bs[slot][ldsOff0]);                      \
        GLL16(gB1 + kt_, &Bs[slot][ldsOff1]);                      \
    } while (0)

    // swapped operands (R6/R15-verified): lane owns row = i*16+(lane&15),
    // cols = j*16 + (lane>>4)*4 + 0..3
#define COMPUTE(b)                                                                              \
    do {                                                                                        \
        f16x8 af[4], bg[4];                                                                     \
        _Pragma("unroll") for (int i = 0; i < 4; i++) af[i] = *(const f16x8*)&As[b][offA[i]];   \
        _Pragma("unroll") for (int j = 0; j < 4; j++) bg[j] = *(const f16x8*)&Bs[b][offB[j]];   \
        _Pragma("unroll") for (int i = 0; i < 4; i++)                                           \
        _Pragma("unroll") for (int j = 0; j < 4; j++)                                           \
            acc[i][j] = __builtin_amdgcn_mfma_f32_16x16x32_f16(bg[j], af[i], acc[i][j], 0, 0, 0); \
    } while (0)

    const int erow = lane & 15;
    const int ecq = (lane >> 4) * 4;
#define EPILOGUE(ti)                                                          \
    do {                                                                      \
        size_t mb_ = (size_t)(r0 + (ti)) * 128;                               \
        _Pragma("unroll") for (int i = 0; i < 4; i++) {                       \
            size_t row = mb_ + wr * 64 + i * 16 + erow;                       \
            _Pragma("unroll") for (int j = 0; j < 4; j++) {                   \
                int col = nb + wc * 64 + j * 16 + ecq;                        \
                f16x4 o;                                                      \
                _Pragma("unroll") for (int r = 0; r < 4; r++) {               \
                    float v = acc[i][j][r];                                   \
                    if (RELU) v = fmaxf(v, 0.f);                              \
                    o[r] = (f16)v;                                            \
                }                                                             \
                *(f16x4*)(Out + row * DH + col) = o;                          \
            }                                                                 \
        }                                                                     \
    } while (0)

    // prologue: depth-2
    STAGE_S(0, 0);
    STAGE_S(1, 1);

#pragma unroll
    for (int s = 0; s < 32; ++s) {
        // wait for stage-s to land; s=16,17 must skip past the 16 epilogue stores
        // queued between load groups (16 stores + 4 newer loads = 20)
        if (s == 16 || s == 17) {
            VMCNT(20);
        } else if (s < 30) {
            VMCNT(4);
        } else {
            VMCNT(0);
        }
        __builtin_amdgcn_s_barrier();    // all waves' stage-s landed; s-1 reads done
        if (s < 30) STAGE_S(s + 2, (s + 2) % 3);
        COMPUTE(s % 3);
        if (s == 15) {
            EPILOGUE(0);
#pragma unroll
            for (int i = 0; i < 4; i++)
#pragma unroll
                for (int j = 0; j < 4; j++) acc[i][j] = (f32x4){0.f, 0.f, 0.f, 0.f};
        }
    }
    EPILOGUE(1);
#undef STAGE_S
#undef COMPUTE
#undef EPILOGUE
}

// ---------------- chunked diagonal scan over T (h_t = a*h_{t-1} + u_t) ----------------
__global__ void scan_pass1(const f16* __restrict__ U, const float* __restrict__ Al,
                           float* __restrict__ finals) {
    int tid = blockIdx.x * 256 + threadIdx.x;  // 524288 threads
    int ch = tid & (NCH - 1);
    int c = tid >> 15;
    float a = Al[ch & (DH - 1)];
    const f16* p = U + (size_t)(c * CLEN) * NCH + ch;
    float h = 0.f;
#pragma unroll
    for (int i = 0; i < CLEN; i++) h = fmaf(h, a, (float)p[(size_t)i * NCH]);
    finals[(size_t)c * NCH + ch] = h;
}

// pass3 with pass2 merged (R12, verified): recompute chunk carry from `finals` in-thread.
__global__ void scan_pass3(f16* __restrict__ U, const float* __restrict__ Al,
                           const float* __restrict__ finals) {
    int tid = blockIdx.x * 256 + threadIdx.x;
    int ch = tid & (NCH - 1);
    int c = tid >> 15;
    float a = Al[ch & (DH - 1)];
    float a49 = 1.f;
#pragma unroll
    for (int i = 0; i < CLEN; i++) a49 *= a;
    float carry = 0.f;
    for (int cc = 0; cc < c; cc++)
        carry = fmaf(carry, a49, finals[(size_t)cc * NCH + ch]);
    f16* p = U + (size_t)(c * CLEN) * NCH + ch;
    float h = carry;
#pragma unroll
    for (int i = 0; i < CLEN; i++) {
        h = fmaf(h, a, (float)p[(size_t)i * NCH]);
        p[(size_t)i * NCH] = (f16)h;
    }
}

// ---------------- final dense: out[m,0:2] = (H[m,:] @ Wf) * ACT_INV + bf ----------------
__global__ void final_dense(const f16* __restrict__ H, const float* __restrict__ Wf,
                            const float* __restrict__ bf_, float* __restrict__ out) {
    __shared__ float WfS[DH * 2];
    for (int i = threadIdx.x; i < DH * 2; i += 256) WfS[i] = Wf[i];
    __syncthreads();
    int wave = threadIdx.x >> 6, lane = threadIdx.x & 63;
    size_t m = (size_t)blockIdx.x * 4 + wave;
    f16x8 v = *(const f16x8*)(H + m * DH + lane * 8);
    float d0 = 0.f, d1 = 0.f;
#pragma unroll
    for (int j = 0; j < 8; j++) {
        float hv = (float)v[j];
        int h = lane * 8 + j;
        d0 = fmaf(hv, WfS[h * 2], d0);
        d1 = fmaf(hv, WfS[h * 2 + 1], d1);
    }
#pragma unroll
    for (int off = 32; off; off >>= 1) {
        d0 += __shfl_down(d0, off);
        d1 += __shfl_down(d1, off);
    }
    if (lane == 0) {
        out[m * 2] = fmaf(d0, ACT_INV, bf_[0]);
        out[m * 2 + 1] = fmaf(d1, ACT_INV, bf_[1]);
    }
}

extern "C" void kernel_launch(void* const* d_in, const int* in_sizes, int n_in,
                              void* d_out, int out_size, void* d_ws, size_t ws_size,
                              hipStream_t stream) {
    (void)in_sizes; (void)n_in; (void)out_size; (void)ws_size;
    const float* x   = (const float*)d_in[0];
    const float* W0  = (const float*)d_in[1];
    const float* b0  = (const float*)d_in[2];
    const float* A   = (const float*)d_in[3];
    const float* Bw  = (const float*)d_in[4];
    const float* Cw  = (const float*)d_in[5];
    const float* Wf  = (const float*)d_in[6];
    const float* bfv = (const float*)d_in[7];
    float* out = (float*)d_out;

    char* ws = (char*)d_ws;
    size_t off = 0;
    auto alloc = [&](size_t bytes) {
        void* p = ws + off;
        off += (bytes + 255) & ~(size_t)255;
        return p;
    };
    f16* Bt = (f16*)alloc((size_t)3 * DH * DH * 2);
    f16* Ct = (f16*)alloc((size_t)3 * DH * DH * 2);
    f16* P  = (f16*)alloc((size_t)M_ROWS * DH * 2);  // layer activations
    f16* Q  = (f16*)alloc((size_t)M_ROWS * DH * 2);  // u / hs buffer
    float* finals  = (float*)alloc((size_t)NCH * NCHUNK * 4);

    dim3 b256(256);
    prep_weights<<<dim3(16, 16, 6), dim3(32, 8), 0, stream>>>(Bw, Cw, Bt, Ct);
    dense0_kernel<<<M_ROWS * 64 / 256, b256, 0, stream>>>(x, W0, b0, P);
    for (int l = 0; l < 3; l++) {
        const float* Al = A + l * DH;
        gemm_p<0><<<dim3(784), b256, 0, stream>>>(P, Bt + (size_t)l * DH * DH, Q);
        scan_pass1<<<NCH * NCHUNK / 256, b256, 0, stream>>>(Q, Al, finals);
        scan_pass3<<<NCH * NCHUNK / 256, b256, 0, stream>>>(Q, Al, finals);
        gemm_p<1><<<dim3(784), b256, 0, stream>>>(Q, Ct + (size_t)l * DH * DH, P);
    }
    final_dense<<<M_ROWS / 4, b256, 0, stream>>>(P, Wf, bfv, out);
}

// Round 17
// 399.244 us; speedup vs baseline: 1.9164x; 1.3004x over previous
//
#include <hip/hip_runtime.h>
#include <hip/hip_bf16.h>

typedef _Float16 f16;
typedef f16 f16x4 __attribute__((ext_vector_type(4)));
typedef f16 f16x8 __attribute__((ext_vector_type(8)));
typedef float f32x4 __attribute__((ext_vector_type(4)));

#define T_LEN 784
#define BATCH 64
#define DH 512
#define NCH (BATCH*DH)        // 32768 chains
#define M_ROWS (T_LEN*BATCH)  // 50176
#define NCHUNK 16
#define CLEN 49               // 784 = 16*49

#define ACT_SCALE (1.0f/256.0f)   // power-of-2 activation scaling: exact, keeps fp16 in range
#define ACT_INV   256.0f

// global -> LDS direct DMA, 16B per lane; dest = wave-uniform base + lane*16 (m104/m108)
#define GLL16(g, s)                                                             \
    __builtin_amdgcn_global_load_lds(                                           \
        (const __attribute__((address_space(1))) void*)(g),                     \
        (__attribute__((address_space(3))) void*)(s), 16, 0, 0)

#define VMCNT(n) asm volatile("s_waitcnt vmcnt(" #n ")" ::: "memory")

// ---------------- weight prep: fp32 [k][n] -> fp16 [n][k] (transpose+convert) ----------------
__global__ void prep_weights(const float* __restrict__ B, const float* __restrict__ C,
                             f16* __restrict__ Bt, f16* __restrict__ Ct) {
    __shared__ float tile[32][33];
    int z = blockIdx.z;  // 0..2: B layer z ; 3..5: C layer z-3
    const float* src = (z < 3) ? (B + (size_t)z * DH * DH) : (C + (size_t)(z - 3) * DH * DH);
    f16* dst = (z < 3) ? (Bt + (size_t)z * DH * DH) : (Ct + (size_t)(z - 3) * DH * DH);
    int tx = threadIdx.x, ty = threadIdx.y;  // 32 x 8
    int nb = blockIdx.x * 32, kb = blockIdx.y * 32;
#pragma unroll
    for (int i = 0; i < 4; i++) {
        int k = ty + i * 8;
        tile[k][tx] = src[(size_t)(kb + k) * DH + nb + tx];
    }
    __syncthreads();
#pragma unroll
    for (int i = 0; i < 4; i++) {
        int n = ty + i * 8;
        dst[(size_t)(nb + n) * DH + kb + tx] = (f16)tile[tx][n];
    }
}

// ---------------- first dense: H = relu(x @ W0 + b0) * ACT_SCALE, fp16 out ----------------
__global__ void dense0_kernel(const float* __restrict__ x, const float* __restrict__ W0,
                              const float* __restrict__ b0, f16* __restrict__ H) {
    int tid = blockIdx.x * 256 + threadIdx.x;
    int m = tid >> 6;
    int hb = (tid & 63) * 8;
    float x0 = x[(size_t)m * 2], x1 = x[(size_t)m * 2 + 1];
    f32x4 wa0 = *(const f32x4*)(W0 + hb);
    f32x4 wa1 = *(const f32x4*)(W0 + hb + 4);
    f32x4 wb0 = *(const f32x4*)(W0 + DH + hb);
    f32x4 wb1 = *(const f32x4*)(W0 + DH + hb + 4);
    f32x4 c0 = *(const f32x4*)(b0 + hb);
    f32x4 c1 = *(const f32x4*)(b0 + hb + 4);
    f16x8 o;
#pragma unroll
    for (int j = 0; j < 4; j++) {
        float v = fmaxf(fmaf(x0, wa0[j], fmaf(x1, wb0[j], c0[j])), 0.f) * ACT_SCALE;
        o[j] = (f16)v;
    }
#pragma unroll
    for (int j = 0; j < 4; j++) {
        float v = fmaxf(fmaf(x0, wa1[j], fmaf(x1, wb1[j], c1[j])), 0.f) * ACT_SCALE;
        o[4 + j] = (f16)v;
    }
    *(f16x8*)(H + (size_t)m * DH + hb) = o;
}

// ---------------- fp16 MFMA GEMM: Out[M,512] = A[M,512] @ Bt^T (Bt is [n][k]) ----------------
// R12 config EXACTLY (best verified: 361.3us total, gemm 44.7-45.4us): 128x128 tile, BK=32,
// 4 waves (2x2, 64x64/wave), 256 threads, 3-buffer LDS ring (48KB -> 3 blocks/CU), depth-2
// prefetch, counted VMCNT(4) + one barrier per K-step. XOR-swizzled k-slots (rule #21).
// ONE change vs R12: swapped-operand mfma(bg, af) (verified R6/R15/R16) -> lane owns 4
// CONSECUTIVE out-cols of one row, epilogue = 16x 8B f16x4 stores instead of 64x 2B scalar.
// Register-neutral (same acc count); K-loop untouched.
template <int RELU>
__global__ __launch_bounds__(256) void gemm_k(const f16* __restrict__ A,
                                              const f16* __restrict__ Bt,
                                              f16* __restrict__ Out) {
    __shared__ __align__(16) f16 As[3][128 * 32];
    __shared__ __align__(16) f16 Bs[3][128 * 32];
    const int tid = threadIdx.x;
    const int lane = tid & 63;
    const int wave = tid >> 6;
    const int wr = wave >> 1, wc = wave & 1;
    const size_t mb = (size_t)blockIdx.x * 128;
    const int nb = blockIdx.y * 128;

    // staging: wave w, round p covers rows [p*64 + w*16, +16); lane l -> row +(l>>2), slot l&3
    const int rl = lane >> 2, sl = lane & 3;
    const int ssl = sl ^ ((rl >> 1) & 3);             // pre-swizzled source k-slot
    const int rowS0 = wave * 16 + rl;                 // round 0 row
    const int rowS1 = 64 + wave * 16 + rl;            // round 1 row
    const f16* gA0 = A + (mb + rowS0) * DH + ssl * 8;
    const f16* gA1 = A + (mb + rowS1) * DH + ssl * 8;
    const f16* gB0 = Bt + (size_t)(nb + rowS0) * DH + ssl * 8;
    const f16* gB1 = Bt + (size_t)(nb + rowS1) * DH + ssl * 8;
    const int ldsOff0 = (wave * 16) * 32;             // wave-uniform LDS elem offsets
    const int ldsOff1 = (64 + wave * 16) * 32;

    // fragment read offsets: row = w*64 + i*16 + rA, k-slot kq swizzled by f(rA)
    const int rA = lane & 15, kq = lane >> 4;
    const int fsl = kq ^ ((rA >> 1) & 3);
    int offA[4], offB[4];
#pragma unroll
    for (int i = 0; i < 4; i++) offA[i] = (wr * 64 + i * 16 + rA) * 32 + fsl * 8;
#pragma unroll
    for (int j = 0; j < 4; j++) offB[j] = (wc * 64 + j * 16 + rA) * 32 + fsl * 8;

    f32x4 acc[4][4] = {};

#define STAGE(b, kt)                        \
    do {                                    \
        GLL16(gA0 + (kt), &As[b][ldsOff0]); \
        GLL16(gA1 + (kt), &As[b][ldsOff1]); \
        GLL16(gB0 + (kt), &Bs[b][ldsOff0]); \
        GLL16(gB1 + (kt), &Bs[b][ldsOff1]); \
    } while (0)

    // swapped operands (R6/R15/R16-verified): lane owns row = i*16+(lane&15),
    // cols = j*16 + (lane>>4)*4 + 0..3 (consecutive)
#define COMPUTE(b)                                                                              \
    do {                                                                                        \
        f16x8 af[4], bg[4];                                                                     \
        _Pragma("unroll") for (int i = 0; i < 4; i++) af[i] = *(const f16x8*)&As[b][offA[i]];   \
        _Pragma("unroll") for (int j = 0; j < 4; j++) bg[j] = *(const f16x8*)&Bs[b][offB[j]];   \
        _Pragma("unroll") for (int i = 0; i < 4; i++)                                           \
        _Pragma("unroll") for (int j = 0; j < 4; j++)                                           \
            acc[i][j] = __builtin_amdgcn_mfma_f32_16x16x32_f16(bg[j], af[i], acc[i][j], 0, 0, 0); \
    } while (0)

    // prologue: depth-2 (8 vmem ops/wave in flight)
    STAGE(0, 0);
    STAGE(1, 32);

#pragma unroll
    for (int t = 0; t < 15; ++t) {
        VMCNT(4);                        // own stage-t landed; stage t+1 stays in flight
        __builtin_amdgcn_s_barrier();    // everyone's stage-t landed; t-1 reads done
        if (t < 14) STAGE((t + 2) % 3, (t + 2) * 32);
        COMPUTE(t % 3);
    }
    VMCNT(0);
    __builtin_amdgcn_s_barrier();
    COMPUTE(0);  // t = 15 -> buf 0
#undef STAGE
#undef COMPUTE

    // epilogue: lane owns row = i*16 + (lane&15); cols = j*16 + (lane>>4)*4 + 0..3 -> 8B stores
    const int erow = lane & 15;
    const int ecq = (lane >> 4) * 4;
#pragma unroll
    for (int i = 0; i < 4; i++) {
        size_t row = mb + wr * 64 + i * 16 + erow;
#pragma unroll
        for (int j = 0; j < 4; j++) {
            int col = nb + wc * 64 + j * 16 + ecq;
            f16x4 o;
#pragma unroll
            for (int r = 0; r < 4; r++) {
                float v = acc[i][j][r];
                if (RELU) v = fmaxf(v, 0.f);
                o[r] = (f16)v;
            }
            *(f16x4*)(Out + row * DH + col) = o;
        }
    }
}

// ---------------- chunked diagonal scan over T (h_t = a*h_{t-1} + u_t) ----------------
__global__ void scan_pass1(const f16* __restrict__ U, const float* __restrict__ Al,
                           float* __restrict__ finals) {
    int tid = blockIdx.x * 256 + threadIdx.x;  // 524288 threads
    int ch = tid & (NCH - 1);
    int c = tid >> 15;
    float a = Al[ch & (DH - 1)];
    const f16* p = U + (size_t)(c * CLEN) * NCH + ch;
    float h = 0.f;
#pragma unroll
    for (int i = 0; i < CLEN; i++) h = fmaf(h, a, (float)p[(size_t)i * NCH]);
    finals[(size_t)c * NCH + ch] = h;
}

// pass3 with pass2 merged (R12, verified): recompute chunk carry from `finals` in-thread.
__global__ void scan_pass3(f16* __restrict__ U, const float* __restrict__ Al,
                           const float* __restrict__ finals) {
    int tid = blockIdx.x * 256 + threadIdx.x;
    int ch = tid & (NCH - 1);
    int c = tid >> 15;
    float a = Al[ch & (DH - 1)];
    float a49 = 1.f;
#pragma unroll
    for (int i = 0; i < CLEN; i++) a49 *= a;
    float carry = 0.f;
    for (int cc = 0; cc < c; cc++)
        carry = fmaf(carry, a49, finals[(size_t)cc * NCH + ch]);
    f16* p = U + (size_t)(c * CLEN) * NCH + ch;
    float h = carry;
#pragma unroll
    for (int i = 0; i < CLEN; i++) {
        h = fmaf(h, a, (float)p[(size_t)i * NCH]);
        p[(size_t)i * NCH] = (f16)h;
    }
}

// ---------------- final dense: out[m,0:2] = (H[m,:] @ Wf) * ACT_INV + bf ----------------
__global__ void final_dense(const f16* __restrict__ H, const float* __restrict__ Wf,
                            const float* __restrict__ bf_, float* __restrict__ out) {
    __shared__ float WfS[DH * 2];
    for (int i = threadIdx.x; i < DH * 2; i += 256) WfS[i] = Wf[i];
    __syncthreads();
    int wave = threadIdx.x >> 6, lane = threadIdx.x & 63;
    size_t m = (size_t)blockIdx.x * 4 + wave;
    f16x8 v = *(const f16x8*)(H + m * DH + lane * 8);
    float d0 = 0.f, d1 = 0.f;
#pragma unroll
    for (int j = 0; j < 8; j++) {
        float hv = (float)v[j];
        int h = lane * 8 + j;
        d0 = fmaf(hv, WfS[h * 2], d0);
        d1 = fmaf(hv, WfS[h * 2 + 1], d1);
    }
#pragma unroll
    for (int off = 32; off; off >>= 1) {
        d0 += __shfl_down(d0, off);
        d1 += __shfl_down(d1, off);
    }
    if (lane == 0) {
        out[m * 2] = fmaf(d0, ACT_INV, bf_[0]);
        out[m * 2 + 1] = fmaf(d1, ACT_INV, bf_[1]);
    }
}

extern "C" void kernel_launch(void* const* d_in, const int* in_sizes, int n_in,
                              void* d_out, int out_size, void* d_ws, size_t ws_size,
                              hipStream_t stream) {
    (void)in_sizes; (void)n_in; (void)out_size; (void)ws_size;
    const float* x   = (const float*)d_in[0];
    const float* W0  = (const float*)d_in[1];
    const float* b0  = (const float*)d_in[2];
    const float* A   = (const float*)d_in[3];
    const float* Bw  = (const float*)d_in[4];
    const float* Cw  = (const float*)d_in[5];
    const float* Wf  = (const float*)d_in[6];
    const float* bfv = (const float*)d_in[7];
    float* out = (float*)d_out;

    char* ws = (char*)d_ws;
    size_t off = 0;
    auto alloc = [&](size_t bytes) {
        void* p = ws + off;
        off += (bytes + 255) & ~(size_t)255;
        return p;
    };
    f16* Bt = (f16*)alloc((size_t)3 * DH * DH * 2);
    f16* Ct = (f16*)alloc((size_t)3 * DH * DH * 2);
    f16* P  = (f16*)alloc((size_t)M_ROWS * DH * 2);  // layer activations
    f16* Q  = (f16*)alloc((size_t)M_ROWS * DH * 2);  // u / hs buffer
    float* finals  = (float*)alloc((size_t)NCH * NCHUNK * 4);

    dim3 b256(256);
    prep_weights<<<dim3(16, 16, 6), dim3(32, 8), 0, stream>>>(Bw, Cw, Bt, Ct);
    dense0_kernel<<<M_ROWS * 64 / 256, b256, 0, stream>>>(x, W0, b0, P);
    for (int l = 0; l < 3; l++) {
        const float* Al = A + l * DH;
        gemm_k<0><<<dim3(M_ROWS / 128, 4), b256, 0, stream>>>(P, Bt + (size_t)l * DH * DH, Q);
        scan_pass1<<<NCH * NCHUNK / 256, b256, 0, stream>>>(Q, Al, finals);
        scan_pass3<<<NCH * NCHUNK / 256, b256, 0, stream>>>(Q, Al, finals);
        gemm_k<1><<<dim3(M_ROWS / 128, 4), b256, 0, stream>>>(Q, Ct + (size_t)l * DH * DH, P);
    }
    final_dense<<<M_ROWS / 4, b256, 0, stream>>>(P, Wf, bfv, out);
}

// Round 19
// 359.956 us; speedup vs baseline: 2.1256x; 1.1091x over previous
//
#include <hip/hip_runtime.h>
#include <hip/hip_bf16.h>

typedef _Float16 f16;
typedef f16 f16x8 __attribute__((ext_vector_type(8)));
typedef float f32x4 __attribute__((ext_vector_type(4)));

#define T_LEN 784
#define BATCH 64
#define DH 512
#define NCH (BATCH*DH)        // 32768 chains
#define M_ROWS (T_LEN*BATCH)  // 50176
#define NCHUNK 16
#define CLEN 49               // 784 = 16*49

#define ACT_SCALE (1.0f/256.0f)   // power-of-2 activation scaling: exact, keeps fp16 in range
#define ACT_INV   256.0f

// global -> LDS direct DMA, 16B per lane; dest = wave-uniform base + lane*16 (m104/m108)
#define GLL16(g, s)                                                             \
    __builtin_amdgcn_global_load_lds(                                           \
        (const __attribute__((address_space(1))) void*)(g),                     \
        (__attribute__((address_space(3))) void*)(s), 16, 0, 0)

#define VMCNT(n) asm volatile("s_waitcnt vmcnt(" #n ")" ::: "memory")

// ---------------- weight prep: fp32 [k][n] -> fp16 [n][k] (transpose+convert) ----------------
__global__ void prep_weights(const float* __restrict__ B, const float* __restrict__ C,
                             f16* __restrict__ Bt, f16* __restrict__ Ct) {
    __shared__ float tile[32][33];
    int z = blockIdx.z;  // 0..2: B layer z ; 3..5: C layer z-3
    const float* src = (z < 3) ? (B + (size_t)z * DH * DH) : (C + (size_t)(z - 3) * DH * DH);
    f16* dst = (z < 3) ? (Bt + (size_t)z * DH * DH) : (Ct + (size_t)(z - 3) * DH * DH);
    int tx = threadIdx.x, ty = threadIdx.y;  // 32 x 8
    int nb = blockIdx.x * 32, kb = blockIdx.y * 32;
#pragma unroll
    for (int i = 0; i < 4; i++) {
        int k = ty + i * 8;
        tile[k][tx] = src[(size_t)(kb + k) * DH + nb + tx];
    }
    __syncthreads();
#pragma unroll
    for (int i = 0; i < 4; i++) {
        int n = ty + i * 8;
        dst[(size_t)(nb + n) * DH + kb + tx] = (f16)tile[tx][n];
    }
}

// ---------------- first dense: H = relu(x @ W0 + b0) * ACT_SCALE, fp16 out ----------------
__global__ void dense0_kernel(const float* __restrict__ x, const float* __restrict__ W0,
                              const float* __restrict__ b0, f16* __restrict__ H) {
    int tid = blockIdx.x * 256 + threadIdx.x;
    int m = tid >> 6;
    int hb = (tid & 63) * 8;
    float x0 = x[(size_t)m * 2], x1 = x[(size_t)m * 2 + 1];
    f32x4 wa0 = *(const f32x4*)(W0 + hb);
    f32x4 wa1 = *(const f32x4*)(W0 + hb + 4);
    f32x4 wb0 = *(const f32x4*)(W0 + DH + hb);
    f32x4 wb1 = *(const f32x4*)(W0 + DH + hb + 4);
    f32x4 c0 = *(const f32x4*)(b0 + hb);
    f32x4 c1 = *(const f32x4*)(b0 + hb + 4);
    f16x8 o;
#pragma unroll
    for (int j = 0; j < 4; j++) {
        float v = fmaxf(fmaf(x0, wa0[j], fmaf(x1, wb0[j], c0[j])), 0.f) * ACT_SCALE;
        o[j] = (f16)v;
    }
#pragma unroll
    for (int j = 0; j < 4; j++) {
        float v = fmaxf(fmaf(x0, wa1[j], fmaf(x1, wb1[j], c1[j])), 0.f) * ACT_SCALE;
        o[4 + j] = (f16)v;
    }
    *(f16x8*)(H + (size_t)m * DH + hb) = o;
}

// ---------------- fp16 MFMA GEMM: Out[M,512] = A[M,512] @ Bt^T (Bt is [n][k]) ----------------
// R12 config EXACTLY (best verified: 361.3us total, gemm 44.7-45.4us): 128x128 tile, BK=32,
// 4 waves (2x2, 64x64/wave), 256 threads, 3-buffer LDS ring (48KB -> 3 blocks/CU), depth-2
// prefetch, counted VMCNT(4) + one barrier per K-step. XOR-swizzled k-slots (rule #21:
// linear LDS dest + pre-swizzled source + swizzled read). Sharp local optimum: 10
// structural variants (R6-R17) all regressed; swapped-operand epilogue costs +6us (R17).
template <int RELU>
__global__ __launch_bounds__(256) void gemm_k(const f16* __restrict__ A,
                                              const f16* __restrict__ Bt,
                                              f16* __restrict__ Out) {
    __shared__ __align__(16) f16 As[3][128 * 32];
    __shared__ __align__(16) f16 Bs[3][128 * 32];
    const int tid = threadIdx.x;
    const int lane = tid & 63;
    const int wave = tid >> 6;
    const int wr = wave >> 1, wc = wave & 1;
    const size_t mb = (size_t)blockIdx.x * 128;
    const int nb = blockIdx.y * 128;

    // staging: wave w, round p covers rows [p*64 + w*16, +16); lane l -> row +(l>>2), slot l&3
    const int rl = lane >> 2, sl = lane & 3;
    const int ssl = sl ^ ((rl >> 1) & 3);             // pre-swizzled source k-slot
    const int rowS0 = wave * 16 + rl;                 // round 0 row
    const int rowS1 = 64 + wave * 16 + rl;            // round 1 row
    const f16* gA0 = A + (mb + rowS0) * DH + ssl * 8;
    const f16* gA1 = A + (mb + rowS1) * DH + ssl * 8;
    const f16* gB0 = Bt + (size_t)(nb + rowS0) * DH + ssl * 8;
    const f16* gB1 = Bt + (size_t)(nb + rowS1) * DH + ssl * 8;
    const int ldsOff0 = (wave * 16) * 32;             // wave-uniform LDS elem offsets
    const int ldsOff1 = (64 + wave * 16) * 32;

    // fragment read offsets: row = w*64 + i*16 + rA, k-slot kq swizzled by f(rA)
    const int rA = lane & 15, kq = lane >> 4;
    const int fsl = kq ^ ((rA >> 1) & 3);
    int offA[4], offB[4];
#pragma unroll
    for (int i = 0; i < 4; i++) offA[i] = (wr * 64 + i * 16 + rA) * 32 + fsl * 8;
#pragma unroll
    for (int j = 0; j < 4; j++) offB[j] = (wc * 64 + j * 16 + rA) * 32 + fsl * 8;

    f32x4 acc[4][4] = {};

#define STAGE(b, kt)                        \
    do {                                    \
        GLL16(gA0 + (kt), &As[b][ldsOff0]); \
        GLL16(gA1 + (kt), &As[b][ldsOff1]); \
        GLL16(gB0 + (kt), &Bs[b][ldsOff0]); \
        GLL16(gB1 + (kt), &Bs[b][ldsOff1]); \
    } while (0)

#define COMPUTE(b)                                                                              \
    do {                                                                                        \
        f16x8 af[4], bg[4];                                                                     \
        _Pragma("unroll") for (int i = 0; i < 4; i++) af[i] = *(const f16x8*)&As[b][offA[i]];   \
        _Pragma("unroll") for (int j = 0; j < 4; j++) bg[j] = *(const f16x8*)&Bs[b][offB[j]];   \
        _Pragma("unroll") for (int i = 0; i < 4; i++)                                           \
        _Pragma("unroll") for (int j = 0; j < 4; j++)                                           \
            acc[i][j] = __builtin_amdgcn_mfma_f32_16x16x32_f16(af[i], bg[j], acc[i][j], 0, 0, 0); \
    } while (0)

    // prologue: depth-2 (8 vmem ops/wave in flight)
    STAGE(0, 0);
    STAGE(1, 32);

#pragma unroll
    for (int t = 0; t < 15; ++t) {
        VMCNT(4);                        // own stage-t landed; stage t+1 stays in flight
        __builtin_amdgcn_s_barrier();    // everyone's stage-t landed; t-1 reads done
        if (t < 14) STAGE((t + 2) % 3, (t + 2) * 32);
        COMPUTE(t % 3);
    }
    VMCNT(0);
    __builtin_amdgcn_s_barrier();
    COMPUTE(0);  // t = 15 -> buf 0
#undef STAGE
#undef COMPUTE

    // epilogue: D frag layout col=lane&15, row=(lane>>4)*4+reg
    const int crow = (lane >> 4) * 4;
    const int ccol = lane & 15;
#pragma unroll
    for (int i = 0; i < 4; i++)
#pragma unroll
        for (int j = 0; j < 4; j++) {
#pragma unroll
            for (int r = 0; r < 4; r++) {
                size_t row = mb + wr * 64 + i * 16 + crow + r;
                int col = nb + wc * 64 + j * 16 + ccol;
                float v = acc[i][j][r];
                if (RELU) v = fmaxf(v, 0.f);
                Out[row * DH + col] = (f16)v;
            }
        }
}

// ---------------- chunked diagonal scan over T (h_t = a*h_{t-1} + u_t) ----------------
__global__ void scan_pass1(const f16* __restrict__ U, const float* __restrict__ Al,
                           float* __restrict__ finals) {
    int tid = blockIdx.x * 256 + threadIdx.x;  // 524288 threads
    int ch = tid & (NCH - 1);
    int c = tid >> 15;
    float a = Al[ch & (DH - 1)];
    const f16* p = U + (size_t)(c * CLEN) * NCH + ch;
    float h = 0.f;
#pragma unroll
    for (int i = 0; i < CLEN; i++) h = fmaf(h, a, (float)p[(size_t)i * NCH]);
    finals[(size_t)c * NCH + ch] = h;
}

// pass3 with pass2 merged (R12, verified): recompute chunk carry from `finals` in-thread.
__global__ void scan_pass3(f16* __restrict__ U, const float* __restrict__ Al,
                           const float* __restrict__ finals) {
    int tid = blockIdx.x * 256 + threadIdx.x;
    int ch = tid & (NCH - 1);
    int c = tid >> 15;
    float a = Al[ch & (DH - 1)];
    float a49 = 1.f;
#pragma unroll
    for (int i = 0; i < CLEN; i++) a49 *= a;
    float carry = 0.f;
    for (int cc = 0; cc < c; cc++)
        carry = fmaf(carry, a49, finals[(size_t)cc * NCH + ch]);
    f16* p = U + (size_t)(c * CLEN) * NCH + ch;
    float h = carry;
#pragma unroll
    for (int i = 0; i < CLEN; i++) {
        h = fmaf(h, a, (float)p[(size_t)i * NCH]);
        p[(size_t)i * NCH] = (f16)h;
    }
}

// ---------------- final dense: out[m,0:2] = (H[m,:] @ Wf) * ACT_INV + bf ----------------
__global__ void final_dense(const f16* __restrict__ H, const float* __restrict__ Wf,
                            const float* __restrict__ bf_, float* __restrict__ out) {
    __shared__ float WfS[DH * 2];
    for (int i = threadIdx.x; i < DH * 2; i += 256) WfS[i] = Wf[i];
    __syncthreads();
    int wave = threadIdx.x >> 6, lane = threadIdx.x & 63;
    size_t m = (size_t)blockIdx.x * 4 + wave;
    f16x8 v = *(const f16x8*)(H + m * DH + lane * 8);
    float d0 = 0.f, d1 = 0.f;
#pragma unroll
    for (int j = 0; j < 8; j++) {
        float hv = (float)v[j];
        int h = lane * 8 + j;
        d0 = fmaf(hv, WfS[h * 2], d0);
        d1 = fmaf(hv, WfS[h * 2 + 1], d1);
    }
#pragma unroll
    for (int off = 32; off; off >>= 1) {
        d0 += __shfl_down(d0, off);
        d1 += __shfl_down(d1, off);
    }
    if (lane == 0) {
        out[m * 2] = fmaf(d0, ACT_INV, bf_[0]);
        out[m * 2 + 1] = fmaf(d1, ACT_INV, bf_[1]);
    }
}

extern "C" void kernel_launch(void* const* d_in, const int* in_sizes, int n_in,
                              void* d_out, int out_size, void* d_ws, size_t ws_size,
                              hipStream_t stream) {
    (void)in_sizes; (void)n_in; (void)out_size; (void)ws_size;
    const float* x   = (const float*)d_in[0];
    const float* W0  = (const float*)d_in[1];
    const float* b0  = (const float*)d_in[2];
    const float* A   = (const float*)d_in[3];
    const float* Bw  = (const float*)d_in[4];
    const float* Cw  = (const float*)d_in[5];
    const float* Wf  = (const float*)d_in[6];
    const float* bfv = (const float*)d_in[7];
    float* out = (float*)d_out;

    char* ws = (char*)d_ws;
    size_t off = 0;
    auto alloc = [&](size_t bytes) {
        void* p = ws + off;
        off += (bytes + 255) & ~(size_t)255;
        return p;
    };
    f16* Bt = (f16*)alloc((size_t)3 * DH * DH * 2);
    f16* Ct = (f16*)alloc((size_t)3 * DH * DH * 2);
    f16* P  = (f16*)alloc((size_t)M_ROWS * DH * 2);  // layer activations
    f16* Q  = (f16*)alloc((size_t)M_ROWS * DH * 2);  // u / hs buffer
    float* finals  = (float*)alloc((size_t)NCH * NCHUNK * 4);

    dim3 b256(256);
    prep_weights<<<dim3(16, 16, 6), dim3(32, 8), 0, stream>>>(Bw, Cw, Bt, Ct);
    dense0_kernel<<<M_ROWS * 64 / 256, b256, 0, stream>>>(x, W0, b0, P);
    for (int l = 0; l < 3; l++) {
        const float* Al = A + l * DH;
        gemm_k<0><<<dim3(M_ROWS / 128, 4), b256, 0, stream>>>(P, Bt + (size_t)l * DH * DH, Q);
        scan_pass1<<<NCH * NCHUNK / 256, b256, 0, stream>>>(Q, Al, finals);
        scan_pass3<<<NCH * NCHUNK / 256, b256, 0, stream>>>(Q, Al, finals);
        gemm_k<1><<<dim3(M_ROWS / 128, 4), b256, 0, stream>>>(Q, Ct + (size_t)l * DH * DH, P);
    }
    final_dense<<<M_ROWS / 4, b256, 0, stream>>>(P, Wf, bfv, out);
}